// Round 1
// baseline (130.882 us; speedup 1.0000x reference)
//
#include <hip/hip_runtime.h>
#include <math.h>

#define Bsz 16
#define Nn  128
#define NFd 64
#define NDd 100
#define NHd 64

#define DM_LD 101   // LDS stride for dm [j][101]  -> banks (5j+d)%32, conflict-free reads
#define G_LD  132   // LDS stride for gated [h][132] -> 16B-aligned rows, b128 reads

// ---------------- kernel 1: atom_h[b,j,h] = b_cf[h] + sum_f AF[b,j,f] * W_cf[f,h] ----------------
__global__ __launch_bounds__(256) void atomh_kernel(
    const float* __restrict__ AF, const float* __restrict__ Wcf,
    const float* __restrict__ bcf, float* __restrict__ atomh) {
  int t   = threadIdx.x;
  int row = blockIdx.x * 4 + (t >> 6);   // b*N + j  (0..2047)
  int h   = t & 63;
  const float* af = AF + (size_t)row * NFd;
  float a0 = 0.f, a1 = 0.f, a2 = 0.f, a3 = 0.f;
  #pragma unroll 4
  for (int f = 0; f < NFd; f += 4) {
    a0 += af[f + 0] * Wcf[(f + 0) * NHd + h];
    a1 += af[f + 1] * Wcf[(f + 1) * NHd + h];
    a2 += af[f + 2] * Wcf[(f + 2) * NHd + h];
    a3 += af[f + 3] * Wcf[(f + 3) * NHd + h];
  }
  atomh[(size_t)row * NHd + h] = bcf[h] + ((a0 + a1) + (a2 + a3));
}

// ---------------- kernel 2: per (b,i) block ----------------
// phase 1: dist_h[j,h] = dm[j,:] . W_df[:,h] + b_df[h]         (M=128 j, N=64 h, K=100)
// gate   : *= atom_h[b,j,h]
// phase 2: pre[j,f]  = gated[j,:] . W_fc[:,f]                  (M=128 j, N=64 f, K=64)
// out    : out[b,i,f] = sum_j tanh(pre[j,f]*mask[j]) + AF[b,i,f]
__global__ __launch_bounds__(256, 2) void dtnn_main_kernel(
    const float* __restrict__ AF,
    const float* __restrict__ DM,
    const float* __restrict__ MASK,
    const float* __restrict__ Wdf,
    const float* __restrict__ Wfc,
    const float* __restrict__ bdf,
    const float* __restrict__ atomh,
    float* __restrict__ out) {
  __shared__ float buf[Nn * DM_LD];      // 12928 f32 = 51.7 KB; reused for gated [h][G_LD] (8448 f32)
  __shared__ float masklds[Nn];
  __shared__ float red[16 * 64];         // 4 KB

  const int t  = threadIdx.x;
  const int bi = blockIdx.x;             // b*N + i
  const int b  = bi >> 7;
  const int th = t & 15;                 // h-group (phase1) / f-group (phase2): cols 4*th..4*th+3
  const int tj = t >> 4;                 // j-group: rows 8*tj..8*tj+7

  // ---- stage dm[j][d] -> LDS [j][DM_LD], coalesced float4 global loads ----
  const float* dmblk = DM + (size_t)bi * (Nn * NDd);
  for (int v = t; v < (Nn * NDd) / 4; v += 256) {
    int j  = v / (NDd / 4);        // 25 float4 per row
    int d0 = (v % (NDd / 4)) * 4;
    float4 x = *reinterpret_cast<const float4*>(dmblk + j * NDd + d0);
    float* p = &buf[j * DM_LD + d0];
    p[0] = x.x; p[1] = x.y; p[2] = x.z; p[3] = x.w;
  }
  if (t < Nn) masklds[t] = MASK[(size_t)bi * Nn + t];
  __syncthreads();

  // ---- phase 1: register tile 8j x 4h ----
  float acc1[8][4];
  float4 bdf4 = *reinterpret_cast<const float4*>(bdf + 4 * th);
  #pragma unroll
  for (int jj = 0; jj < 8; ++jj) {
    acc1[jj][0] = bdf4.x; acc1[jj][1] = bdf4.y; acc1[jj][2] = bdf4.z; acc1[jj][3] = bdf4.w;
  }
  const float* dmb = buf + (tj * 8) * DM_LD;
  #pragma unroll 2
  for (int d = 0; d < NDd; ++d) {
    float4 w = *reinterpret_cast<const float4*>(Wdf + d * NHd + 4 * th);  // L1/L2-hot
    #pragma unroll
    for (int jj = 0; jj < 8; ++jj) {
      float dv = dmb[jj * DM_LD + d];
      acc1[jj][0] += dv * w.x;
      acc1[jj][1] += dv * w.y;
      acc1[jj][2] += dv * w.z;
      acc1[jj][3] += dv * w.w;
    }
  }

  // ---- gate with atom_h[b, j, h] (note: indexed by j, broadcast over i) ----
  #pragma unroll
  for (int jj = 0; jj < 8; ++jj) {
    int j = tj * 8 + jj;
    float4 ah = *reinterpret_cast<const float4*>(atomh + ((size_t)(b * Nn + j)) * NHd + 4 * th);
    acc1[jj][0] *= ah.x; acc1[jj][1] *= ah.y; acc1[jj][2] *= ah.z; acc1[jj][3] *= ah.w;
  }
  __syncthreads();   // all waves done READING dm before buf is overwritten

  // ---- write gated transposed: buf[h][j], stride G_LD ----
  #pragma unroll
  for (int jj = 0; jj < 8; ++jj) {
    int j = tj * 8 + jj;
    #pragma unroll
    for (int hh = 0; hh < 4; ++hh) {
      buf[(4 * th + hh) * G_LD + j] = acc1[jj][hh];
    }
  }
  __syncthreads();

  // ---- phase 2: register tile 8j x 4f ----
  float acc2[8][4];
  #pragma unroll
  for (int jj = 0; jj < 8; ++jj)
    for (int ff = 0; ff < 4; ++ff) acc2[jj][ff] = 0.f;

  #pragma unroll 2
  for (int h = 0; h < NHd; ++h) {
    float4 w  = *reinterpret_cast<const float4*>(Wfc + h * NFd + 4 * th);  // L1/L2-hot
    float4 g0 = *reinterpret_cast<const float4*>(&buf[h * G_LD + 8 * tj]);      // ds_read_b128
    float4 g1 = *reinterpret_cast<const float4*>(&buf[h * G_LD + 8 * tj + 4]);  // ds_read_b128
    float g[8] = {g0.x, g0.y, g0.z, g0.w, g1.x, g1.y, g1.z, g1.w};
    #pragma unroll
    for (int jj = 0; jj < 8; ++jj) {
      acc2[jj][0] += g[jj] * w.x;
      acc2[jj][1] += g[jj] * w.y;
      acc2[jj][2] += g[jj] * w.z;
      acc2[jj][3] += g[jj] * w.w;
    }
  }

  // ---- mask, tanh, partial sum over this lane's 8 j ----
  float part[4] = {0.f, 0.f, 0.f, 0.f};
  #pragma unroll
  for (int jj = 0; jj < 8; ++jj) {
    float m = masklds[tj * 8 + jj];
    #pragma unroll
    for (int ff = 0; ff < 4; ++ff) part[ff] += tanhf(acc2[jj][ff] * m);
  }

  // ---- block reduction over the 16 tj groups ----
  #pragma unroll
  for (int ff = 0; ff < 4; ++ff) red[tj * 64 + 4 * th + ff] = part[ff];
  __syncthreads();
  if (t < 64) {
    float s = 0.f;
    #pragma unroll
    for (int g = 0; g < 16; ++g) s += red[g * 64 + t];
    out[(size_t)bi * NFd + t] = s + AF[(size_t)bi * NFd + t];
  }
}

extern "C" void kernel_launch(void* const* d_in, const int* in_sizes, int n_in,
                              void* d_out, int out_size, void* d_ws, size_t ws_size,
                              hipStream_t stream) {
  const float* AF   = (const float*)d_in[0];
  const float* DM   = (const float*)d_in[1];
  const float* MASK = (const float*)d_in[2];
  const float* Wcf  = (const float*)d_in[3];
  const float* Wdf  = (const float*)d_in[4];
  const float* Wfc  = (const float*)d_in[5];
  const float* bcf  = (const float*)d_in[6];
  const float* bdf  = (const float*)d_in[7];
  float* out   = (float*)d_out;
  float* atomh = (float*)d_ws;   // B*N*NH f32 = 512 KB

  atomh_kernel<<<(Bsz * Nn) / 4, 256, 0, stream>>>(AF, Wcf, bcf, atomh);
  dtnn_main_kernel<<<Bsz * Nn, 256, 0, stream>>>(AF, DM, MASK, Wdf, Wfc, bdf, atomh, out);
}

// Round 2
// 44.478 us; speedup vs baseline: 2.9426x; 2.9426x over previous
//
#include <hip/hip_runtime.h>
#include <math.h>

#define Bsz 16
#define Nn  128
#define NFd 64
#define NDd 100
#define NHd 64

typedef __attribute__((ext_vector_type(8))) short bf16x8;
typedef __attribute__((ext_vector_type(4))) float f32x4;

__device__ __forceinline__ ushort f2bf(float f) {
  // RNE f32 -> bf16 (inputs are finite; no NaN handling needed)
  unsigned u = __builtin_bit_cast(unsigned, f);
  u = (u + 0x7FFFu + ((u >> 16) & 1u)) >> 16;
  return (ushort)u;
}

// ---------------- prep kernel ----------------
// blocks [0,512):   atomh[b,j,h] = b_cf[h] + sum_f AF[b,j,f]*W_cf[f,h]   (f32 -> ws)
// blocks [512,544): pack W_df -> bf16 MFMA-B fragments, K zero-padded to 128
// blocks [544,560): pack W_fc -> bf16 MFMA-B fragments (K=64)
__global__ __launch_bounds__(256) void prep_kernel(
    const float* __restrict__ AF, const float* __restrict__ Wcf,
    const float* __restrict__ bcf, const float* __restrict__ Wdf,
    const float* __restrict__ Wfc, float* __restrict__ atomh,
    ushort* __restrict__ wdfp, ushort* __restrict__ wfcp) {
  int t = threadIdx.x;
  int blk = blockIdx.x;
  if (blk < 512) {
    int row = blk * 4 + (t >> 6);        // b*N + j
    int h = t & 63;
    const float* af = AF + (size_t)row * NFd;
    float a0 = 0.f, a1 = 0.f, a2 = 0.f, a3 = 0.f;
    #pragma unroll 4
    for (int f = 0; f < NFd; f += 4) {
      a0 += af[f + 0] * Wcf[(f + 0) * NHd + h];
      a1 += af[f + 1] * Wcf[(f + 1) * NHd + h];
      a2 += af[f + 2] * Wcf[(f + 2) * NHd + h];
      a3 += af[f + 3] * Wcf[(f + 3) * NHd + h];
    }
    atomh[(size_t)row * NHd + h] = bcf[h] + ((a0 + a1) + (a2 + a3));
  } else if (blk < 544) {
    // wdfp[(grp*64 + col)*8 + e] = bf16(Wdf[k= grp*8+e ][col]), 0 if k>=100
    int idx = (blk - 512) * 256 + t;     // [0, 8192)
    int e = idx & 7;
    int col = (idx >> 3) & 63;
    int grp = idx >> 9;
    int k = grp * 8 + e;
    float v = (k < NDd) ? Wdf[k * NHd + col] : 0.f;
    wdfp[idx] = f2bf(v);
  } else {
    int idx = (blk - 544) * 256 + t;     // [0, 4096)
    int e = idx & 7;
    int col = (idx >> 3) & 63;
    int grp = idx >> 9;
    int k = grp * 8 + e;
    wfcp[idx] = f2bf(Wfc[k * NFd + col]);
  }
}

// ---------------- main kernel: one block per (b,i) ----------------
// phase1: dist_h[j,h] = dm[j,:].W_df[:,h] + b_df[h]   (MFMA bf16, K padded to 128)
// gate:   *= atomh[b,j,h]  (f32)
// phase2: pre[j,f] = gated[j,:].W_fc[:,f]             (MFMA bf16, K=64)
// out[b,i,f] = sum_j tanh(pre[j,f]*mask[j]) + AF[b,i,f]
__global__ __launch_bounds__(256, 4) void dtnn_main_kernel(
    const float* __restrict__ AF,
    const float* __restrict__ DM,
    const float* __restrict__ MASK,
    const float* __restrict__ bdf,
    const float* __restrict__ atomh,
    const ushort* __restrict__ wdfp,
    const ushort* __restrict__ wfcp,
    float* __restrict__ out) {
  // dm tile: [128 j][128 k] bf16, XOR-swizzled: elem = j*128 + (k ^ ((j&7)<<3))
  // reused in phase2 as gated [128 j][64 h]:    elem = j*64  + (h ^ ((j&7)<<3))
  __shared__ ushort dmbuf[Nn * 128];   // 32 KB
  __shared__ float masklds[Nn];
  __shared__ float red[4 * 64];

  const int t  = threadIdx.x;
  const int bi = blockIdx.x;           // b*N + i
  const int b  = bi >> 7;
  const int w  = t >> 6;               // wave 0..3 -> rows 32w..32w+31
  const int p  = t & 15;               // lane&15
  const int q  = (t >> 4) & 3;         // lane>>4

  // ---- stage DM[b,i,:,:] -> bf16 LDS (swizzled), zero-pad k=100..127 ----
  const float* dmblk = DM + (size_t)bi * (Nn * NDd);
  #pragma unroll
  for (int i = 0; i < 16; ++i) {
    int v = i * 256 + t;               // [0, 4096): 32 4-elem chunks per row
    int j = v >> 5;
    int c = v & 31;
    int d0 = c * 4;
    ushort4 w4;
    if (c < 25) {
      float4 x = *reinterpret_cast<const float4*>(dmblk + j * NDd + d0);
      w4.x = f2bf(x.x); w4.y = f2bf(x.y); w4.z = f2bf(x.z); w4.w = f2bf(x.w);
    } else {
      w4.x = 0; w4.y = 0; w4.z = 0; w4.w = 0;
    }
    *reinterpret_cast<ushort4*>(&dmbuf[j * 128 + (d0 ^ ((j & 7) << 3))]) = w4;
  }
  if (t < Nn) masklds[t] = MASK[(size_t)bi * Nn + t];
  __syncthreads();

  // ---- phase 1: C[128j x 64h], wave w owns j-tiles {2w, 2w+1}, all 4 h-tiles ----
  f32x4 acc1[2][4];
  #pragma unroll
  for (int ht = 0; ht < 4; ++ht) {
    float bv = bdf[ht * 16 + p];
    #pragma unroll
    for (int jt = 0; jt < 2; ++jt) acc1[jt][ht] = (f32x4){bv, bv, bv, bv};
  }
  const bf16x8* wdfv = reinterpret_cast<const bf16x8*>(wdfp);
  #pragma unroll
  for (int ks = 0; ks < 4; ++ks) {
    bf16x8 bf[4];
    #pragma unroll
    for (int ht = 0; ht < 4; ++ht) bf[ht] = wdfv[(ks * 4 + q) * 64 + ht * 16 + p];
    #pragma unroll
    for (int jt = 0; jt < 2; ++jt) {
      int j = (2 * w + jt) * 16 + p;                 // A row = lane&15
      int k0 = ks * 32 + q * 8;                      // A k-chunk = lane>>4
      bf16x8 a = *reinterpret_cast<const bf16x8*>(&dmbuf[j * 128 + (k0 ^ ((j & 7) << 3))]);
      #pragma unroll
      for (int ht = 0; ht < 4; ++ht)
        acc1[jt][ht] = __builtin_amdgcn_mfma_f32_16x16x32_bf16(a, bf[ht], acc1[jt][ht], 0, 0, 0);
    }
  }

  // ---- gate: acc1[j][h] *= atomh[b, j, h]   (D layout: row j = 16jt+4q+r, col h = 16ht+p) ----
  #pragma unroll
  for (int jt = 0; jt < 2; ++jt) {
    int jbase = (2 * w + jt) * 16 + 4 * q;
    #pragma unroll
    for (int ht = 0; ht < 4; ++ht) {
      const float* ap = atomh + ((size_t)(b * Nn + jbase)) * NHd + ht * 16 + p;
      #pragma unroll
      for (int r = 0; r < 4; ++r) acc1[jt][ht][r] *= ap[r * NHd];
    }
  }
  __syncthreads();   // all phase-1 LDS reads done before overwrite

  // ---- write gated (bf16, swizzled) ----
  #pragma unroll
  for (int jt = 0; jt < 2; ++jt) {
    #pragma unroll
    for (int r = 0; r < 4; ++r) {
      int j = (2 * w + jt) * 16 + 4 * q + r;
      int sw = (j & 7) << 3;
      #pragma unroll
      for (int ht = 0; ht < 4; ++ht) {
        int h = ht * 16 + p;
        dmbuf[j * 64 + (h ^ sw)] = f2bf(acc1[jt][ht][r]);
      }
    }
  }
  __syncthreads();

  // ---- phase 2: C2[128j x 64f], K=64 ----
  f32x4 acc2[2][4];
  #pragma unroll
  for (int jt = 0; jt < 2; ++jt)
    #pragma unroll
    for (int ft = 0; ft < 4; ++ft) acc2[jt][ft] = (f32x4){0.f, 0.f, 0.f, 0.f};
  const bf16x8* wfcv = reinterpret_cast<const bf16x8*>(wfcp);
  #pragma unroll
  for (int ks = 0; ks < 2; ++ks) {
    bf16x8 bf[4];
    #pragma unroll
    for (int ft = 0; ft < 4; ++ft) bf[ft] = wfcv[(ks * 4 + q) * 64 + ft * 16 + p];
    #pragma unroll
    for (int jt = 0; jt < 2; ++jt) {
      int j = (2 * w + jt) * 16 + p;
      int h0 = ks * 32 + q * 8;
      bf16x8 a = *reinterpret_cast<const bf16x8*>(&dmbuf[j * 64 + (h0 ^ ((j & 7) << 3))]);
      #pragma unroll
      for (int ft = 0; ft < 4; ++ft)
        acc2[jt][ft] = __builtin_amdgcn_mfma_f32_16x16x32_bf16(a, bf[ft], acc2[jt][ft], 0, 0, 0);
    }
  }

  // ---- mask, tanh, reduce over j ----
  float s[4] = {0.f, 0.f, 0.f, 0.f};
  #pragma unroll
  for (int jt = 0; jt < 2; ++jt) {
    #pragma unroll
    for (int r = 0; r < 4; ++r) {
      int j = (2 * w + jt) * 16 + 4 * q + r;
      float m = masklds[j];
      #pragma unroll
      for (int ft = 0; ft < 4; ++ft) s[ft] += tanhf(acc2[jt][ft][r] * m);
    }
  }
  #pragma unroll
  for (int ft = 0; ft < 4; ++ft) {
    s[ft] += __shfl_xor(s[ft], 16, 64);
    s[ft] += __shfl_xor(s[ft], 32, 64);
  }
  if (q == 0) {
    #pragma unroll
    for (int ft = 0; ft < 4; ++ft) red[w * 64 + ft * 16 + p] = s[ft];
  }
  __syncthreads();
  if (t < 64) {
    float tot = red[t] + red[64 + t] + red[128 + t] + red[192 + t];
    out[(size_t)bi * NFd + t] = tot + AF[(size_t)bi * NFd + t];
  }
}

extern "C" void kernel_launch(void* const* d_in, const int* in_sizes, int n_in,
                              void* d_out, int out_size, void* d_ws, size_t ws_size,
                              hipStream_t stream) {
  const float* AF   = (const float*)d_in[0];
  const float* DM   = (const float*)d_in[1];
  const float* MASK = (const float*)d_in[2];
  const float* Wcf  = (const float*)d_in[3];
  const float* Wdf  = (const float*)d_in[4];
  const float* Wfc  = (const float*)d_in[5];
  const float* bcf  = (const float*)d_in[6];
  const float* bdf  = (const float*)d_in[7];
  float* out = (float*)d_out;

  float*  atomh = (float*)d_ws;                                   // 512 KB
  ushort* wdfp  = (ushort*)((char*)d_ws + 524288);                // 16 KB (K padded to 128)
  ushort* wfcp  = (ushort*)((char*)d_ws + 524288 + 16384);        // 8 KB

  prep_kernel<<<560, 256, 0, stream>>>(AF, Wcf, bcf, Wdf, Wfc, atomh, wdfp, wfcp);
  dtnn_main_kernel<<<Bsz * Nn, 256, 0, stream>>>(AF, DM, MASK, bdf, atomh, wdfp, wfcp, out);
}